// Round 10
// baseline (287.197 us; speedup 1.0000x reference)
//
#include <hip/hip_runtime.h>
#include <stdint.h>

// GumbelVQ forward, MI355X — round 10.
// R9 result: z_q (f32) PASSED -> layout/readback model correct. indices absmax
// 8125 ~= expected max|U-U'| over 8192 rows -> ALL indices wrong -> wrong RNG
// scheme. Fix: JAX >= 0.4.36 defaults jax_threefry_partitionable=True, which
// uses per-element counter mode: element j gets threefry((0,42),(hi=0,lo=j)),
// 32-bit output = w0 ^ w1 (xor-fold), NOT the legacy split-halves scheme.
//
//   d_out (float[73731]):
//     [0..65535]     z_q f32 (B,D,H,W)         — gvq10_gather
//     [65536..73727] indices as f32 values     — gvq10_argmax
//     [73728..73730] commit, perplexity, usage — gvq10_stats
// Inputs (float32): z_e (8,8,32,32), embedding (8192,8), proj_w (8192,8).

#define NCODES 8192
#define NROWS  8192

__device__ __forceinline__ uint32_t gvq10_rotl(uint32_t x, uint32_t r) {
    return (x << r) | (x >> (32u - r));
}

// Threefry-2x32, 20 rounds, key = (0, 42)  [jax.random.key(42)]
__device__ __forceinline__ void gvq10_threefry(uint32_t& x0, uint32_t& x1) {
    const uint32_t ks0 = 0u, ks1 = 42u, ks2 = 42u ^ 0x1BD11BDAu;
    x0 += ks0; x1 += ks1;
#define TFR(r) { x0 += x1; x1 = gvq10_rotl(x1, r); x1 ^= x0; }
    TFR(13u) TFR(15u) TFR(26u) TFR(6u)   x0 += ks1; x1 += ks2 + 1u;
    TFR(17u) TFR(29u) TFR(16u) TFR(24u)  x0 += ks2; x1 += ks0 + 2u;
    TFR(13u) TFR(15u) TFR(26u) TFR(6u)   x0 += ks0; x1 += ks1 + 3u;
    TFR(17u) TFR(29u) TFR(16u) TFR(24u)  x0 += ks1; x1 += ks2 + 4u;
    TFR(13u) TFR(15u) TFR(26u) TFR(6u)   x0 += ks2; x1 += ks0 + 5u;
#undef TFR
}

// jax.random.uniform(f32, 1e-20, 1.0) -> gumbel -log(-log(u)).
__device__ __forceinline__ float gvq10_gumbel(uint32_t bits) {
    float f = __uint_as_float((bits >> 9) | 0x3f800000u) - 1.0f;
    float u = (f == 0.0f) ? 1e-20f : f;
    return -logf(-logf(u));
}

// Kernel 1: one block per row n. Partitionable counter-mode threefry:
// element j = n*8192+k -> threefry((0,42),(0,j)), bits = w0 ^ w1.
__global__ __launch_bounds__(256) void gvq10_argmax(const float* __restrict__ z_e,
                                                    const float* __restrict__ proj_w,
                                                    float* __restrict__ out) {
    __shared__ float sv[256]; __shared__ int si[256];
    const int tid = threadIdx.x;
    const int n = blockIdx.x;            // 0..8191
    const int b = n >> 10, r = n & 1023;

    float z[8];
#pragma unroll
    for (int d = 0; d < 8; ++d)
        z[d] = z_e[b * 8192 + d * 1024 + r];

    const float4* wr = (const float4*)proj_w;
    float best = -INFINITY;
    int bi = 0;
    const uint32_t base = (uint32_t)n * (uint32_t)NCODES;

    for (int k = tid; k < NCODES; k += 256) {
        float4 wa = wr[2 * k];
        float4 wb = wr[2 * k + 1];
        float dot = 0.0f;
        dot = fmaf(z[0], wa.x, dot); dot = fmaf(z[1], wa.y, dot);
        dot = fmaf(z[2], wa.z, dot); dot = fmaf(z[3], wa.w, dot);
        dot = fmaf(z[4], wb.x, dot); dot = fmaf(z[5], wb.y, dot);
        dot = fmaf(z[6], wb.z, dot); dot = fmaf(z[7], wb.w, dot);

        uint32_t x0 = 0u;                // counts_hi (j < 2^32)
        uint32_t x1 = base + (uint32_t)k; // counts_lo = flat element index
        gvq10_threefry(x0, x1);
        float v = dot + gvq10_gumbel(x0 ^ x1);   // 32-bit path: xor-fold

        if (v > best) { best = v; bi = k; }      // strict > : first max wins
    }

    sv[tid] = best; si[tid] = bi;
    __syncthreads();
    for (int s = 128; s > 0; s >>= 1) {
        if (tid < s) {
            if (sv[tid + s] > sv[tid] ||
                (sv[tid + s] == sv[tid] && si[tid + s] < si[tid])) {
                sv[tid] = sv[tid + s]; si[tid] = si[tid + s];
            }
        }
        __syncthreads();
    }
    if (tid == 0) out[65536 + n] = (float)si[0];
}

// Kernel 2: single block. LDS histogram -> perplexity/usage; commit loss from
// z_e re-read + emb gather. No global scratch.
__global__ __launch_bounds__(256) void gvq10_stats(const float* __restrict__ z_e,
                                                   const float* __restrict__ emb,
                                                   float* __restrict__ out) {
    __shared__ int counts[NCODES];        // 32 KiB
    __shared__ float fred[256];
    __shared__ float hred[256];
    __shared__ int ired[256];
    const int tid = threadIdx.x;

    for (int k = tid; k < NCODES; k += 256) counts[k] = 0;
    __syncthreads();

    float sq = 0.0f;
    for (int n = tid; n < NROWS; n += 256) {
        int idx = (int)out[65536 + n] & 8191;
        atomicAdd(&counts[idx], 1);
        const int b = n >> 10, r = n & 1023;
        const float4* ep = (const float4*)(emb + idx * 8);
        float4 ea = ep[0], eb = ep[1];
        float e[8] = {ea.x, ea.y, ea.z, ea.w, eb.x, eb.y, eb.z, eb.w};
#pragma unroll
        for (int d = 0; d < 8; ++d) {
            float diff = z_e[b * 8192 + d * 1024 + r] - e[d];
            sq = fmaf(diff, diff, sq);
        }
    }
    __syncthreads();

    float h = 0.0f; int used = 0;
    for (int k = tid; k < NCODES; k += 256) {
        int c = counts[k];
        float avg = (float)c * (1.0f / 8192.0f);
        h += avg * logf(avg + 1e-10f);
        used += (c > 0) ? 1 : 0;
    }
    fred[tid] = sq; hred[tid] = h; ired[tid] = used;
    __syncthreads();
    for (int t = 128; t > 0; t >>= 1) {
        if (tid < t) {
            fred[tid] += fred[tid + t];
            hred[tid] += hred[tid + t];
            ired[tid] += ired[tid + t];
        }
        __syncthreads();
    }
    if (tid == 0) {
        out[73728] = 0.25f * fred[0] * (1.0f / 65536.0f);   // commit loss
        out[73729] = expf(-hred[0]);                        // perplexity
        out[73730] = (float)ired[0] * (1.0f / 8192.0f);     // usage
    }
}

// Kernel 3: z_q = emb[idx], f32, (B,D,H,W) layout.
__global__ __launch_bounds__(256) void gvq10_gather(const float* __restrict__ emb,
                                                    float* __restrict__ out) {
    const int n = blockIdx.x * 256 + threadIdx.x;   // grid 32 -> n in [0,8192)
    const int b = n >> 10, r = n & 1023;
    const int idx = (int)out[65536 + n] & 8191;

    const float4* ep = (const float4*)(emb + idx * 8);
    float4 ea = ep[0], eb = ep[1];
    float e[8] = {ea.x, ea.y, ea.z, ea.w, eb.x, eb.y, eb.z, eb.w};

#pragma unroll
    for (int d = 0; d < 8; ++d)
        out[b * 8192 + d * 1024 + r] = e[d];        // (B,D,H,W)
}

extern "C" void kernel_launch(void* const* d_in, const int* in_sizes, int n_in,
                              void* d_out, int out_size, void* d_ws, size_t ws_size,
                              hipStream_t stream) {
    const float* z_e   = (const float*)d_in[0];
    const float* emb   = (const float*)d_in[1];
    const float* projw = (const float*)d_in[2];
    float* out = (float*)d_out;

    gvq10_argmax<<<8192, 256, 0, stream>>>(z_e, projw, out);
    gvq10_stats <<<1,    256, 0, stream>>>(z_e, emb, out);
    gvq10_gather<<<32,   256, 0, stream>>>(emb, out);
}

// Round 11
// 257.021 us; speedup vs baseline: 1.1174x; 1.1174x over previous
//
#include <hip/hip_runtime.h>
#include <stdint.h>

// GumbelVQ forward, MI355X — round 11 (first optimization round; R10 passed @287us).
// R10 counters: argmax 232us, VALUBusy~100%, ~272 VALU inst/element — the two
// accurate OCML logf calls dominate (~180 inst). Changes:
//  1. fast gumbel: g = -ln2*log2(ln2*(-log2(u))) via __log2f (v_log_f32, ~5 inst)
//  2. 4 rows/block: proj_w L2 traffic 2GB -> 0.5GB, fewer load/addr ops per element
//  3. z_q gather fused into argmax epilogue (kernel dropped); stats @1024 threads
//
//   d_out (float[73731]):
//     [0..65535]     z_q f32 (B,D,H,W)          — gvq11_argmax epilogue
//     [65536..73727] indices as f32 values      — gvq11_argmax epilogue
//     [73728..73730] commit, perplexity, usage  — gvq11_stats
// Inputs (float32): z_e (8,8,32,32), embedding (8192,8), proj_w (8192,8).

#define NCODES 8192
#define NROWS  8192
#define RPB    4        // rows per block
#define LN2F   0.69314718055994530942f

__device__ __forceinline__ uint32_t gvq11_rotl(uint32_t x, uint32_t r) {
    return (x << r) | (x >> (32u - r));
}

// Threefry-2x32, 20 rounds, key = (0, 42)  [jax.random.key(42)]
__device__ __forceinline__ void gvq11_threefry(uint32_t& x0, uint32_t& x1) {
    const uint32_t ks0 = 0u, ks1 = 42u, ks2 = 42u ^ 0x1BD11BDAu;
    x0 += ks0; x1 += ks1;
#define TFR(r) { x0 += x1; x1 = gvq11_rotl(x1, r); x1 ^= x0; }
    TFR(13u) TFR(15u) TFR(26u) TFR(6u)   x0 += ks1; x1 += ks2 + 1u;
    TFR(17u) TFR(29u) TFR(16u) TFR(24u)  x0 += ks2; x1 += ks0 + 2u;
    TFR(13u) TFR(15u) TFR(26u) TFR(6u)   x0 += ks0; x1 += ks1 + 3u;
    TFR(17u) TFR(29u) TFR(16u) TFR(24u)  x0 += ks1; x1 += ks2 + 4u;
    TFR(13u) TFR(15u) TFR(26u) TFR(6u)   x0 += ks2; x1 += ks0 + 5u;
#undef TFR
}

// jax.random.uniform(f32, 1e-20, 1.0) -> gumbel -log(-log(u)).
// Fast path: ln u = ln2*log2(u) with HW v_log_f32 (1 ULP). ~5 inst vs ~180.
__device__ __forceinline__ float gvq11_gumbel(uint32_t bits) {
    float f = __uint_as_float((bits >> 9) | 0x3f800000u) - 1.0f;
    float u = (f == 0.0f) ? 1e-20f : f;
    float t = -LN2F * __log2f(u);        // -log(u) > 0
    return -LN2F * __log2f(t);           // -log(-log(u))
}

// Kernel 1: 4 rows per block (n, n+2048, n+4096, n+6144). Partitionable
// counter-mode threefry: element j=row*8192+k -> tf((0,42),(0,j)), bits=w0^w1.
// Epilogue writes idx (f32) AND the row's z_q = emb[idx].
__global__ __launch_bounds__(256) void gvq11_argmax(const float* __restrict__ z_e,
                                                    const float* __restrict__ proj_w,
                                                    const float* __restrict__ emb,
                                                    float* __restrict__ out) {
    __shared__ float sv[RPB][256];
    __shared__ int   si[RPB][256];
    const int tid = threadIdx.x;

    float z[RPB][8];
#pragma unroll
    for (int q = 0; q < RPB; ++q) {
        const int n = blockIdx.x + q * 2048;
        const int b = n >> 10, r = n & 1023;
#pragma unroll
        for (int d = 0; d < 8; ++d)
            z[q][d] = z_e[b * 8192 + d * 1024 + r];
    }

    const float4* wr = (const float4*)proj_w;
    float best[RPB];
    int   bi[RPB];
#pragma unroll
    for (int q = 0; q < RPB; ++q) { best[q] = -INFINITY; bi[q] = 0; }

    const uint32_t base = (uint32_t)blockIdx.x * (uint32_t)NCODES;

    for (int k = tid; k < NCODES; k += 256) {
        float4 wa = wr[2 * k];
        float4 wb = wr[2 * k + 1];
#pragma unroll
        for (int q = 0; q < RPB; ++q) {
            float dot = 0.0f;
            dot = fmaf(z[q][0], wa.x, dot); dot = fmaf(z[q][1], wa.y, dot);
            dot = fmaf(z[q][2], wa.z, dot); dot = fmaf(z[q][3], wa.w, dot);
            dot = fmaf(z[q][4], wb.x, dot); dot = fmaf(z[q][5], wb.y, dot);
            dot = fmaf(z[q][6], wb.z, dot); dot = fmaf(z[q][7], wb.w, dot);

            uint32_t x0 = 0u;                                    // counts_hi
            uint32_t x1 = base + (uint32_t)(q * 2048 * NCODES) + (uint32_t)k;
            gvq11_threefry(x0, x1);
            float v = dot + gvq11_gumbel(x0 ^ x1);               // xor-fold

            if (v > best[q]) { best[q] = v; bi[q] = k; }         // first max wins
        }
    }

#pragma unroll
    for (int q = 0; q < RPB; ++q) { sv[q][tid] = best[q]; si[q][tid] = bi[q]; }
    __syncthreads();
    for (int s = 128; s > 0; s >>= 1) {
        if (tid < s) {
#pragma unroll
            for (int q = 0; q < RPB; ++q) {
                if (sv[q][tid + s] > sv[q][tid] ||
                    (sv[q][tid + s] == sv[q][tid] && si[q][tid + s] < si[q][tid])) {
                    sv[q][tid] = sv[q][tid + s]; si[q][tid] = si[q][tid + s];
                }
            }
        }
        __syncthreads();
    }

    if (tid < RPB) {
        const int n = blockIdx.x + tid * 2048;
        const int idx = si[tid][0];
        out[65536 + n] = (float)idx;
        const float4* ep = (const float4*)(emb + idx * 8);
        float4 ea = ep[0], eb = ep[1];
        const int b = n >> 10, r = n & 1023;
        out[b * 8192 + 0 * 1024 + r] = ea.x;
        out[b * 8192 + 1 * 1024 + r] = ea.y;
        out[b * 8192 + 2 * 1024 + r] = ea.z;
        out[b * 8192 + 3 * 1024 + r] = ea.w;
        out[b * 8192 + 4 * 1024 + r] = eb.x;
        out[b * 8192 + 5 * 1024 + r] = eb.y;
        out[b * 8192 + 6 * 1024 + r] = eb.z;
        out[b * 8192 + 7 * 1024 + r] = eb.w;
    }
}

// Kernel 2: single block, 1024 threads. LDS histogram -> perplexity/usage;
// commit loss from z_e re-read + emb gather.
__global__ __launch_bounds__(1024) void gvq11_stats(const float* __restrict__ z_e,
                                                    const float* __restrict__ emb,
                                                    float* __restrict__ out) {
    __shared__ int counts[NCODES];        // 32 KiB
    __shared__ float fred[1024];
    __shared__ float hred[1024];
    __shared__ int ired[1024];
    const int tid = threadIdx.x;

    for (int k = tid; k < NCODES; k += 1024) counts[k] = 0;
    __syncthreads();

    float sq = 0.0f;
    for (int n = tid; n < NROWS; n += 1024) {
        int idx = (int)out[65536 + n] & 8191;
        atomicAdd(&counts[idx], 1);
        const int b = n >> 10, r = n & 1023;
        const float4* ep = (const float4*)(emb + idx * 8);
        float4 ea = ep[0], eb = ep[1];
        float e[8] = {ea.x, ea.y, ea.z, ea.w, eb.x, eb.y, eb.z, eb.w};
#pragma unroll
        for (int d = 0; d < 8; ++d) {
            float diff = z_e[b * 8192 + d * 1024 + r] - e[d];
            sq = fmaf(diff, diff, sq);
        }
    }
    __syncthreads();

    float h = 0.0f; int used = 0;
    for (int k = tid; k < NCODES; k += 1024) {
        int c = counts[k];
        float avg = (float)c * (1.0f / 8192.0f);
        h += avg * logf(avg + 1e-10f);      // 8 iters/thread: accuracy > speed
        used += (c > 0) ? 1 : 0;
    }
    fred[tid] = sq; hred[tid] = h; ired[tid] = used;
    __syncthreads();
    for (int t = 512; t > 0; t >>= 1) {
        if (tid < t) {
            fred[tid] += fred[tid + t];
            hred[tid] += hred[tid + t];
            ired[tid] += ired[tid + t];
        }
        __syncthreads();
    }
    if (tid == 0) {
        out[73728] = 0.25f * fred[0] * (1.0f / 65536.0f);   // commit loss
        out[73729] = expf(-hred[0]);                        // perplexity
        out[73730] = (float)ired[0] * (1.0f / 8192.0f);     // usage
    }
}

extern "C" void kernel_launch(void* const* d_in, const int* in_sizes, int n_in,
                              void* d_out, int out_size, void* d_ws, size_t ws_size,
                              hipStream_t stream) {
    const float* z_e   = (const float*)d_in[0];
    const float* emb   = (const float*)d_in[1];
    const float* projw = (const float*)d_in[2];
    float* out = (float*)d_out;

    gvq11_argmax<<<2048, 256, 0, stream>>>(z_e, projw, emb, out);
    gvq11_stats <<<1,    1024, 0, stream>>>(z_e, emb, out);
}

// Round 12
// 244.909 us; speedup vs baseline: 1.1727x; 1.0495x over previous
//
#include <hip/hip_runtime.h>
#include <stdint.h>

// GumbelVQ forward, MI355X — round 12.
// R11 post-mortem: __log2f lowered to OCML (accurate, ~28 inst) not v_log_f32;
// RPB=4 spilled (VGPR_Count=20 < 32 live floats; WRITE_SIZE 0.25->2.3 MB).
// Fixes: __builtin_amdgcn_logf (HW v_log_f32, log2 semantics); RPB=2 lean state;
// commit-loss fused into argmax epilogue (one float atomic/block into out[73728],
// zeroed by init kernel); stats kernel = histogram+entropy only.
//
//   d_out (float[73731]):
//     [0..65535]     z_q f32 (B,D,H,W)          — argmax epilogue
//     [65536..73727] indices as f32 values      — argmax epilogue
//     [73728..73730] commit, perplexity, usage  — 73728 doubles as commit accum
// Inputs (float32): z_e (8,8,32,32), embedding (8192,8), proj_w (8192,8).

#define NCODES 8192
#define NROWS  8192
#define HALF_OFF 33554432u   // 2^25 = 4096*8192
#define LN2F 0.69314718055994530942f

__device__ __forceinline__ uint32_t gvq12_rotl(uint32_t x, uint32_t r) {
    return (x << r) | (x >> (32u - r));
}

// Threefry-2x32, 20 rounds, key = (0, 42)  [jax.random.key(42)]
__device__ __forceinline__ void gvq12_threefry(uint32_t& x0, uint32_t& x1) {
    const uint32_t ks0 = 0u, ks1 = 42u, ks2 = 42u ^ 0x1BD11BDAu;
    x0 += ks0; x1 += ks1;
#define TFR(r) { x0 += x1; x1 = gvq12_rotl(x1, r); x1 ^= x0; }
    TFR(13u) TFR(15u) TFR(26u) TFR(6u)   x0 += ks1; x1 += ks2 + 1u;
    TFR(17u) TFR(29u) TFR(16u) TFR(24u)  x0 += ks2; x1 += ks0 + 2u;
    TFR(13u) TFR(15u) TFR(26u) TFR(6u)   x0 += ks0; x1 += ks1 + 3u;
    TFR(17u) TFR(29u) TFR(16u) TFR(24u)  x0 += ks1; x1 += ks2 + 4u;
    TFR(13u) TFR(15u) TFR(26u) TFR(6u)   x0 += ks2; x1 += ks0 + 5u;
#undef TFR
}

// jax.random.uniform(f32, 1e-20, 1.0) -> gumbel -log(-log(u)).
// v_log_f32 (log2, ~1 ULP): ln x = LN2 * log2 x. ~6 inst total.
__device__ __forceinline__ float gvq12_gumbel(uint32_t bits) {
    float f = __uint_as_float((bits >> 9) | 0x3f800000u) - 1.0f;
    float u = (f == 0.0f) ? 1e-20f : f;
    float t = -LN2F * __builtin_amdgcn_logf(u);   // -ln(u) > 0
    return -LN2F * __builtin_amdgcn_logf(t);      // -ln(-ln(u))
}

__global__ __launch_bounds__(64) void gvq12_init(float* out) {
    if (threadIdx.x == 0) out[73728] = 0.0f;      // commit accumulator
}

// Kernel 1: 2 rows/block (n, n+4096). Partitionable counter-mode threefry:
// element j=row*8192+k -> tf((0,42),(0,j)), bits = w0^w1. Epilogue writes idx,
// z_q = emb[idx], and block-reduced commit partial (one atomic per block).
__global__ __launch_bounds__(256, 4) void gvq12_argmax(const float* __restrict__ z_e,
                                                       const float* __restrict__ proj_w,
                                                       const float* __restrict__ emb,
                                                       float* __restrict__ out) {
    __shared__ float sv0[256]; __shared__ int si0[256];
    __shared__ float sv1[256]; __shared__ int si1[256];
    __shared__ float ssq[2];
    const int tid = threadIdx.x;
    const int n0 = blockIdx.x;           // 0..4095
    const int n1 = n0 + 4096;
    const int b0 = n0 >> 10, r0 = n0 & 1023;
    const int b1 = n1 >> 10, r1 = n1 & 1023;

    float z0[8], z1[8];
#pragma unroll
    for (int d = 0; d < 8; ++d) {
        z0[d] = z_e[b0 * 8192 + d * 1024 + r0];
        z1[d] = z_e[b1 * 8192 + d * 1024 + r1];
    }

    const float4* wr = (const float4*)proj_w;
    float best0 = -INFINITY, best1 = -INFINITY;
    int bi0 = 0, bi1 = 0;
    const uint32_t base0 = (uint32_t)n0 * (uint32_t)NCODES;

    for (int k = tid; k < NCODES; k += 256) {
        float4 wa = wr[2 * k];
        float4 wb = wr[2 * k + 1];

        float d0 = 0.0f, d1 = 0.0f;
        d0 = fmaf(z0[0], wa.x, d0); d1 = fmaf(z1[0], wa.x, d1);
        d0 = fmaf(z0[1], wa.y, d0); d1 = fmaf(z1[1], wa.y, d1);
        d0 = fmaf(z0[2], wa.z, d0); d1 = fmaf(z1[2], wa.z, d1);
        d0 = fmaf(z0[3], wa.w, d0); d1 = fmaf(z1[3], wa.w, d1);
        d0 = fmaf(z0[4], wb.x, d0); d1 = fmaf(z1[4], wb.x, d1);
        d0 = fmaf(z0[5], wb.y, d0); d1 = fmaf(z1[5], wb.y, d1);
        d0 = fmaf(z0[6], wb.z, d0); d1 = fmaf(z1[6], wb.z, d1);
        d0 = fmaf(z0[7], wb.w, d0); d1 = fmaf(z1[7], wb.w, d1);

        uint32_t a0 = 0u, a1 = base0 + (uint32_t)k;             // row n0
        uint32_t c0 = 0u, c1 = base0 + HALF_OFF + (uint32_t)k;  // row n1
        gvq12_threefry(a0, a1);
        gvq12_threefry(c0, c1);
        float v0 = d0 + gvq12_gumbel(a0 ^ a1);
        float v1 = d1 + gvq12_gumbel(c0 ^ c1);

        if (v0 > best0) { best0 = v0; bi0 = k; }   // strict > : first max wins
        if (v1 > best1) { best1 = v1; bi1 = k; }
    }

    sv0[tid] = best0; si0[tid] = bi0;
    sv1[tid] = best1; si1[tid] = bi1;
    __syncthreads();
    for (int s = 128; s > 0; s >>= 1) {
        if (tid < s) {
            if (sv0[tid + s] > sv0[tid] ||
                (sv0[tid + s] == sv0[tid] && si0[tid + s] < si0[tid])) {
                sv0[tid] = sv0[tid + s]; si0[tid] = si0[tid + s];
            }
            if (sv1[tid + s] > sv1[tid] ||
                (sv1[tid + s] == sv1[tid] && si1[tid + s] < si1[tid])) {
                sv1[tid] = sv1[tid + s]; si1[tid] = si1[tid + s];
            }
        }
        __syncthreads();
    }

    if (tid < 2) {
        const int n = (tid == 0) ? n0 : n1;
        const int idx = (tid == 0) ? si0[0] : si1[0];
        const float* zz = (tid == 0) ? z0 : z1;
        out[65536 + n] = (float)idx;
        const float4* ep = (const float4*)(emb + idx * 8);
        float4 ea = ep[0], eb = ep[1];
        float e[8] = {ea.x, ea.y, ea.z, ea.w, eb.x, eb.y, eb.z, eb.w};
        const int b = n >> 10, r = n & 1023;
        float sq = 0.0f;
#pragma unroll
        for (int d = 0; d < 8; ++d) {
            out[b * 8192 + d * 1024 + r] = e[d];         // z_q (B,D,H,W)
            float diff = zz[d] - e[d];
            sq = fmaf(diff, diff, sq);
        }
        ssq[tid] = sq;
    }
    __syncthreads();
    if (tid == 0) atomicAdd(out + 73728, ssq[0] + ssq[1]);   // commit partial
}

// Kernel 2: single block, 1024 threads. Histogram -> perplexity/usage;
// finalize commit from accumulated sum.
__global__ __launch_bounds__(1024) void gvq12_stats(float* __restrict__ out) {
    __shared__ int counts[NCODES];        // 32 KiB
    __shared__ float hred[1024];
    __shared__ int ired[1024];
    const int tid = threadIdx.x;

    for (int k = tid; k < NCODES; k += 1024) counts[k] = 0;
    __syncthreads();

    for (int n = tid; n < NROWS; n += 1024) {
        int idx = (int)out[65536 + n] & 8191;
        atomicAdd(&counts[idx], 1);
    }
    __syncthreads();

    float h = 0.0f; int used = 0;
    for (int k = tid; k < NCODES; k += 1024) {
        int c = counts[k];
        float avg = (float)c * (1.0f / 8192.0f);
        h += avg * logf(avg + 1e-10f);    // accurate: only 8 iters/thread
        used += (c > 0) ? 1 : 0;
    }
    hred[tid] = h; ired[tid] = used;
    __syncthreads();
    for (int t = 512; t > 0; t >>= 1) {
        if (tid < t) { hred[tid] += hred[tid + t]; ired[tid] += ired[tid + t]; }
        __syncthreads();
    }
    if (tid == 0) {
        float accum = out[73728];
        out[73728] = 0.25f * accum * (1.0f / 65536.0f);   // commit loss
        out[73729] = expf(-hred[0]);                      // perplexity
        out[73730] = (float)ired[0] * (1.0f / 8192.0f);   // usage
    }
}

extern "C" void kernel_launch(void* const* d_in, const int* in_sizes, int n_in,
                              void* d_out, int out_size, void* d_ws, size_t ws_size,
                              hipStream_t stream) {
    const float* z_e   = (const float*)d_in[0];
    const float* emb   = (const float*)d_in[1];
    const float* projw = (const float*)d_in[2];
    float* out = (float*)d_out;

    gvq12_init  <<<1,    64,   0, stream>>>(out);
    gvq12_argmax<<<4096, 256,  0, stream>>>(z_e, projw, emb, out);
    gvq12_stats <<<1,    1024, 0, stream>>>(out);
}

// Round 16
// 244.800 us; speedup vs baseline: 1.1732x; 1.0004x over previous
//
#include <hip/hip_runtime.h>
#include <stdint.h>

// GumbelVQ forward, MI355X — round 16: CONTROL EXPERIMENT.
// R13/R14/R15 (three structurally disjoint kernels) all died with the same
// generic infra ExceptionGroup and no pytest output -> suspected wedged worker
// since R13's d_ws fault. This round resubmits R12 — the known-good 245us
// passing kernel — with symbols renamed and only a lean-gumbel tweak (same
// instruction class). If THIS crashes, the environment is conclusively wedged.
//
//   d_out (float[73731]):
//     [0..65535]     z_q f32 (B,D,H,W)          — argmax epilogue
//     [65536..73727] indices as f32 values      — argmax epilogue
//     [73728..73730] commit, perplexity, usage  — 73728 doubles as commit accum
// Inputs (float32): z_e (8,8,32,32), embedding (8192,8), proj_w (8192,8).

#define NCODES 8192
#define NROWS  8192
#define HALF_OFF 33554432u   // 2^25 = 4096*8192

__device__ __forceinline__ uint32_t gvq16_rotl(uint32_t x, uint32_t r) {
    return (x << r) | (x >> (32u - r));
}

// Threefry-2x32, 20 rounds, key = (0, 42)  [jax.random.key(42)]
__device__ __forceinline__ void gvq16_threefry(uint32_t& x0, uint32_t& x1) {
    const uint32_t ks0 = 0u, ks1 = 42u, ks2 = 42u ^ 0x1BD11BDAu;
    x0 += ks0; x1 += ks1;
#define TFR(r) { x0 += x1; x1 = gvq16_rotl(x1, r); x1 ^= x0; }
    TFR(13u) TFR(15u) TFR(26u) TFR(6u)   x0 += ks1; x1 += ks2 + 1u;
    TFR(17u) TFR(29u) TFR(16u) TFR(24u)  x0 += ks2; x1 += ks0 + 2u;
    TFR(13u) TFR(15u) TFR(26u) TFR(6u)   x0 += ks0; x1 += ks1 + 3u;
    TFR(17u) TFR(29u) TFR(16u) TFR(24u)  x0 += ks1; x1 += ks2 + 4u;
    TFR(13u) TFR(15u) TFR(26u) TFR(6u)   x0 += ks2; x1 += ks0 + 5u;
#undef TFR
}

// gumbel = -ln(-ln u) = C - ln2*log2(-log2 u), C = -ln2*log2(ln2).
// u==0 -> -inf (can never win; ref's clamped -3.83 can't win either).
#define GVQ_C   0.36651292058166435f
#define GVQ_LN2 0.69314718055994530942f
__device__ __forceinline__ float gvq16_gumbel(uint32_t bits) {
    float u = __uint_as_float((bits >> 9) | 0x3f800000u) - 1.0f;
    float l1 = __builtin_amdgcn_logf(u);            // log2(u) <= 0
    float l2 = __builtin_amdgcn_logf(0.0f - l1);    // log2(-log2 u)
    return fmaf(-GVQ_LN2, l2, GVQ_C);
}

__global__ __launch_bounds__(64) void gvq16_init(float* out) {
    if (threadIdx.x == 0) out[73728] = 0.0f;      // commit accumulator
}

// Kernel 1: 2 rows/block (n, n+4096), thread-per-k stride 256 (R12 structure).
__global__ __launch_bounds__(256, 4) void gvq16_argmax(const float* __restrict__ z_e,
                                                       const float* __restrict__ proj_w,
                                                       const float* __restrict__ emb,
                                                       float* __restrict__ out) {
    __shared__ float sv0[256]; __shared__ int si0[256];
    __shared__ float sv1[256]; __shared__ int si1[256];
    __shared__ float ssq[2];
    const int tid = threadIdx.x;
    const int n0 = blockIdx.x;           // 0..4095
    const int n1 = n0 + 4096;
    const int b0 = n0 >> 10, r0 = n0 & 1023;
    const int b1 = n1 >> 10, r1 = n1 & 1023;

    float z0[8], z1[8];
#pragma unroll
    for (int d = 0; d < 8; ++d) {
        z0[d] = z_e[b0 * 8192 + d * 1024 + r0];
        z1[d] = z_e[b1 * 8192 + d * 1024 + r1];
    }

    const float4* wr = (const float4*)proj_w;
    float best0 = -INFINITY, best1 = -INFINITY;
    int bi0 = 0, bi1 = 0;
    const uint32_t base0 = (uint32_t)n0 * (uint32_t)NCODES;

    for (int k = tid; k < NCODES; k += 256) {
        float4 wa = wr[2 * k];
        float4 wb = wr[2 * k + 1];

        float d0 = 0.0f, d1 = 0.0f;
        d0 = fmaf(z0[0], wa.x, d0); d1 = fmaf(z1[0], wa.x, d1);
        d0 = fmaf(z0[1], wa.y, d0); d1 = fmaf(z1[1], wa.y, d1);
        d0 = fmaf(z0[2], wa.z, d0); d1 = fmaf(z1[2], wa.z, d1);
        d0 = fmaf(z0[3], wa.w, d0); d1 = fmaf(z1[3], wa.w, d1);
        d0 = fmaf(z0[4], wb.x, d0); d1 = fmaf(z1[4], wb.x, d1);
        d0 = fmaf(z0[5], wb.y, d0); d1 = fmaf(z1[5], wb.y, d1);
        d0 = fmaf(z0[6], wb.z, d0); d1 = fmaf(z1[6], wb.z, d1);
        d0 = fmaf(z0[7], wb.w, d0); d1 = fmaf(z1[7], wb.w, d1);

        uint32_t a0 = 0u, a1 = base0 + (uint32_t)k;             // row n0
        uint32_t c0 = 0u, c1 = base0 + HALF_OFF + (uint32_t)k;  // row n1
        gvq16_threefry(a0, a1);
        gvq16_threefry(c0, c1);
        float v0 = d0 + gvq16_gumbel(a0 ^ a1);
        float v1 = d1 + gvq16_gumbel(c0 ^ c1);

        if (v0 > best0) { best0 = v0; bi0 = k; }   // strict > : first max wins
        if (v1 > best1) { best1 = v1; bi1 = k; }
    }

    sv0[tid] = best0; si0[tid] = bi0;
    sv1[tid] = best1; si1[tid] = bi1;
    __syncthreads();
    for (int s = 128; s > 0; s >>= 1) {
        if (tid < s) {
            if (sv0[tid + s] > sv0[tid] ||
                (sv0[tid + s] == sv0[tid] && si0[tid + s] < si0[tid])) {
                sv0[tid] = sv0[tid + s]; si0[tid] = si0[tid + s];
            }
            if (sv1[tid + s] > sv1[tid] ||
                (sv1[tid + s] == sv1[tid] && si1[tid + s] < si1[tid])) {
                sv1[tid] = sv1[tid + s]; si1[tid] = si1[tid + s];
            }
        }
        __syncthreads();
    }

    if (tid < 2) {
        const int n = (tid == 0) ? n0 : n1;
        const int idx = (tid == 0) ? si0[0] : si1[0];
        const float* zz = (tid == 0) ? z0 : z1;
        out[65536 + n] = (float)idx;
        const float4* ep = (const float4*)(emb + idx * 8);
        float4 ea = ep[0], eb = ep[1];
        float e[8] = {ea.x, ea.y, ea.z, ea.w, eb.x, eb.y, eb.z, eb.w};
        const int b = n >> 10, r = n & 1023;
        float sq = 0.0f;
#pragma unroll
        for (int d = 0; d < 8; ++d) {
            out[b * 8192 + d * 1024 + r] = e[d];         // z_q (B,D,H,W)
            float diff = zz[d] - e[d];
            sq = fmaf(diff, diff, sq);
        }
        ssq[tid] = sq;
    }
    __syncthreads();
    if (tid == 0) atomicAdd(out + 73728, ssq[0] + ssq[1]);   // commit partial
}

// Kernel 2: single block, 1024 threads. Histogram -> perplexity/usage;
// finalize commit from accumulated sum.
__global__ __launch_bounds__(1024) void gvq16_stats(float* __restrict__ out) {
    __shared__ int counts[NCODES];        // 32 KiB
    __shared__ float hred[1024];
    __shared__ int ired[1024];
    const int tid = threadIdx.x;

    for (int k = tid; k < NCODES; k += 1024) counts[k] = 0;
    __syncthreads();

    for (int n = tid; n < NROWS; n += 1024) {
        int idx = (int)out[65536 + n] & 8191;
        atomicAdd(&counts[idx], 1);
    }
    __syncthreads();

    float h = 0.0f; int used = 0;
    for (int k = tid; k < NCODES; k += 1024) {
        int c = counts[k];
        float avg = (float)c * (1.0f / 8192.0f);
        h += avg * logf(avg + 1e-10f);    // accurate: only 8 iters/thread
        used += (c > 0) ? 1 : 0;
    }
    hred[tid] = h; ired[tid] = used;
    __syncthreads();
    for (int t = 512; t > 0; t >>= 1) {
        if (tid < t) { hred[tid] += hred[tid + t]; ired[tid] += ired[tid + t]; }
        __syncthreads();
    }
    if (tid == 0) {
        float accum = out[73728];
        out[73728] = 0.25f * accum * (1.0f / 65536.0f);   // commit loss
        out[73729] = expf(-hred[0]);                      // perplexity
        out[73730] = (float)ired[0] * (1.0f / 8192.0f);   // usage
    }
}

extern "C" void kernel_launch(void* const* d_in, const int* in_sizes, int n_in,
                              void* d_out, int out_size, void* d_ws, size_t ws_size,
                              hipStream_t stream) {
    const float* z_e   = (const float*)d_in[0];
    const float* emb   = (const float*)d_in[1];
    const float* projw = (const float*)d_in[2];
    float* out = (float*)d_out;

    gvq16_init  <<<1,    64,   0, stream>>>(out);
    gvq16_argmax<<<4096, 256,  0, stream>>>(z_e, projw, emb, out);
    gvq16_stats <<<1,    1024, 0, stream>>>(out);
}